// Round 5
// baseline (231.018 us; speedup 1.0000x reference)
//
#include <hip/hip_runtime.h>
#include <math.h>

#define BB 2
#define CC 512
#define NN 2304
#define NH 8
#define DD 512
#define D3 1536
#define WIDTH 48
#define C1 0.18033688f  // 0.125 * log2(e)

typedef _Float16 h8 __attribute__((ext_vector_type(8)));
typedef _Float16 h4 __attribute__((ext_vector_type(4)));
typedef _Float16 h2 __attribute__((ext_vector_type(2)));
typedef float f4 __attribute__((ext_vector_type(4)));

// ---------------------------------------------------------------------------
// Kernel 0: Fresnel bias table in MFMA C-fragment order, pre-scaled by log2e.
// btf[qtile 36][ktile 36][tid 128][j 32], j = nt*16 + mt*4 + r:
//   query = qtile*64 + (tid>>6)*32 + nt*16 + (tid&15)
//   key   = ktile*64 + mt*16 + ((tid>>4)&3)*4 + r
// ---------------------------------------------------------------------------
__global__ __launch_bounds__(128) void btf_k(const float* __restrict__ wavp,
                                             _Float16* __restrict__ btf)
{
  const int t = threadIdx.x;
  const int qbk = blockIdx.x, ktk = blockIdx.y;
  const int w = t >> 6, quad = (t >> 4) & 3, l15 = t & 15;
  const float pc = 6.283185307179586f / (fabsf(wavp[0]) * (float)WIDTH + 1e-6f);
  _Float16* o = btf + (((size_t)qbk * 36 + ktk) * 128 + t) * 32;
#pragma unroll
  for (int g = 0; g < 4; ++g) {
    h8 v;
#pragma unroll
    for (int e = 0; e < 8; ++e) {
      const int j = g * 8 + e;
      const int nt = j >> 4, mt = (j >> 2) & 3, r = j & 3;
      const int q = qbk * 64 + w * 32 + nt * 16 + l15;
      const int k = ktk * 64 + mt * 16 + quad * 4 + r;
      const float dy = (float)(q / WIDTH) - (float)(k / WIDTH);
      const float dx = (float)(q % WIDTH) - (float)(k % WIDTH);
      const float dist = sqrtf(dy * dy + dx * dx + 1e-8f);
      v[e] = (_Float16)(0.1f * __cosf(dist * pc) * 1.44269504f);
    }
    *(h8*)(o + g * 8) = v;
  }
}

// ---------------------------------------------------------------------------
// Kernel 0b: transpose-convert x[b][c][n] fp32 -> xt[b][n][c] f16
// ---------------------------------------------------------------------------
__global__ __launch_bounds__(256) void tx_k(const float* __restrict__ x,
                                            _Float16* __restrict__ xt)
{
  __shared__ float Ls[32][33];
  const int t = threadIdx.x;
  const int n0 = blockIdx.x * 32, c0 = blockIdx.y * 32, b = blockIdx.z;
#pragma unroll
  for (int p = 0; p < 4; ++p) {
    const int cl = (t >> 5) + p * 8, nl = t & 31;
    Ls[cl][nl] = x[((size_t)b * CC + c0 + cl) * NN + n0 + nl];
  }
  __syncthreads();
#pragma unroll
  for (int p = 0; p < 2; ++p) {
    const int nl = (t >> 4) + p * 16, cl = (t & 15) * 2;
    h2 v = {(_Float16)Ls[cl][nl], (_Float16)Ls[cl + 1][nl]};
    *(h2*)(xt + ((size_t)b * NN + n0 + nl) * CC + c0 + cl) = v;
  }
}

// ---------------------------------------------------------------------------
// Kernel 0c: convert w_qkv and w_out fp32 -> f16
// ---------------------------------------------------------------------------
__global__ __launch_bounds__(256) void convw_k(const float* __restrict__ wq,
                                               const float* __restrict__ wo,
                                               _Float16* __restrict__ wqh,
                                               _Float16* __restrict__ woh)
{
  const int idx = blockIdx.x * 256 + threadIdx.x;
  const int NQ = (D3 * CC) / 4;
  if (idx < NQ) {
    float4 v = *(const float4*)(wq + (size_t)idx * 4);
    h4 o = {(_Float16)v.x, (_Float16)v.y, (_Float16)v.z, (_Float16)v.w};
    *(h4*)(wqh + (size_t)idx * 4) = o;
  } else {
    const int j = idx - NQ;
    float4 v = *(const float4*)(wo + (size_t)j * 4);
    h4 o = {(_Float16)v.x, (_Float16)v.y, (_Float16)v.z, (_Float16)v.w};
    *(h4*)(woh + (size_t)j * 4) = o;
  }
}

// ---------------------------------------------------------------------------
// Kernel 1: qkv MFMA GEMM, barrier-free: A/B fragments loaded directly from
// global (row-major along K). 128x128 tile, 4 waves (2x2 of 64x64), BK=32.
// ---------------------------------------------------------------------------
__global__ __launch_bounds__(256) void qkv_gemm_k(
    const _Float16* __restrict__ xt, const _Float16* __restrict__ wqh,
    _Float16* __restrict__ qb, _Float16* __restrict__ kb,
    _Float16* __restrict__ vb)
{
  const int t = threadIdx.x;
  const int lane = t & 63, w = t >> 6;
  const int l15 = lane & 15, quad = lane >> 4;
  const int wm = w & 1, wn = w >> 1;
  const int n0 = blockIdx.x * 128;
  const int d0 = blockIdx.y * 128;
  const int b  = blockIdx.z;
  const bool isv = (d0 >= 2 * DD);
  const _Float16* xb = xt + (size_t)b * NN * CC;
  const _Float16* wp = wqh + (size_t)(d0 + wm * 64 + l15) * CC + quad * 8;
  const _Float16* xp = xb + (size_t)(n0 + wn * 64 + l15) * CC + quad * 8;

  f4 acc[4][4];
#pragma unroll
  for (int mt = 0; mt < 4; ++mt)
#pragma unroll
    for (int nt = 0; nt < 4; ++nt) acc[mt][nt] = (f4)(0.f);

#pragma unroll 2
  for (int c0 = 0; c0 < CC; c0 += 32) {
    h8 wfr[4], xfr[4];
#pragma unroll
    for (int mt = 0; mt < 4; ++mt)
      wfr[mt] = *(const h8*)(wp + (size_t)mt * 16 * CC + c0);
#pragma unroll
    for (int nt = 0; nt < 4; ++nt)
      xfr[nt] = *(const h8*)(xp + (size_t)nt * 16 * CC + c0);
    if (!isv) {
#pragma unroll
      for (int mt = 0; mt < 4; ++mt)
#pragma unroll
        for (int nt = 0; nt < 4; ++nt)
          acc[mt][nt] = __builtin_amdgcn_mfma_f32_16x16x32_f16(
              wfr[mt], xfr[nt], acc[mt][nt], 0, 0, 0);
    } else {
#pragma unroll
      for (int mt = 0; mt < 4; ++mt)
#pragma unroll
        for (int nt = 0; nt < 4; ++nt)
          acc[mt][nt] = __builtin_amdgcn_mfma_f32_16x16x32_f16(
              xfr[nt], wfr[mt], acc[mt][nt], 0, 0, 0);
    }
  }

  if (!isv) {
    const int which = d0 >> 9;
    _Float16* buf = which == 0 ? qb : kb;
    const int h = ((d0 & 511) >> 6) + wm;
#pragma unroll
    for (int mt = 0; mt < 4; ++mt) {
      const int dh = mt * 16 + quad * 4;
#pragma unroll
      for (int nt = 0; nt < 4; ++nt) {
        const int token = n0 + wn * 64 + nt * 16 + l15;
        h4 o = {(_Float16)acc[mt][nt][0], (_Float16)acc[mt][nt][1],
                (_Float16)acc[mt][nt][2], (_Float16)acc[mt][nt][3]};
        *(h4*)(buf + (((size_t)b * NH + h) * NN + token) * 64 + dh) = o;
      }
    }
  } else {
    const int h = ((d0 - 2 * DD) >> 6) + wm;
#pragma unroll
    for (int mt = 0; mt < 4; ++mt) {
      const int dh = mt * 16 + l15;
#pragma unroll
      for (int nt = 0; nt < 4; ++nt) {
        const int token = n0 + wn * 64 + nt * 16 + quad * 4;
        h4 o = {(_Float16)acc[mt][nt][0], (_Float16)acc[mt][nt][1],
                (_Float16)acc[mt][nt][2], (_Float16)acc[mt][nt][3]};
        *(h4*)(vb + (((size_t)b * NH + h) * 64 + dh) * NN + token) = o;
      }
    }
  }
}

// ---------------------------------------------------------------------------
// Kernel 2: barrier-free MFMA flash attention. 2 waves/block (same 64-q tile,
// same k-range -> L1-shared K/V frag loads straight from global). No-max
// softmax (p = exp2(s*C1 + bias')). Only LDS: wave-private P transpose
// buffer (write->read within one wave, no __syncthreads anywhere).
// ---------------------------------------------------------------------------
__global__ __launch_bounds__(128, 3) void attn_k(
    const _Float16* __restrict__ qb, const _Float16* __restrict__ kb,
    const _Float16* __restrict__ vb, const _Float16* __restrict__ btf,
    _Float16* __restrict__ op, float* __restrict__ lp)
{
  __shared__ _Float16 Ps[2][32][72];
  const int t = threadIdx.x;
  const int lane = t & 63, w = t >> 6;
  const int l15 = lane & 15, quad = lane >> 4;
  const int qt = blockIdx.x >> 1;  // 64-query tile 0..35
  const int s  = blockIdx.x & 1;   // k-split half
  const int h = blockIdx.y, b = blockIdx.z;
  const int n0 = qt * 64 + w * 32;  // this wave's 32-query base
  const size_t base = ((size_t)b * NH + h) * NN * 64;
  const _Float16* qp = qb + base;
  const _Float16* kp = kb + base;
  const _Float16* vp = vb + base;  // [dh][n]

  h8 qf[2][2];
#pragma unroll
  for (int nt = 0; nt < 2; ++nt)
#pragma unroll
    for (int ks = 0; ks < 2; ++ks)
      qf[nt][ks] = *(const h8*)(qp + (size_t)(n0 + nt * 16 + l15) * 64 +
                                ks * 32 + quad * 8);

  f4 oc[4][2];
#pragma unroll
  for (int mt = 0; mt < 4; ++mt)
#pragma unroll
    for (int nt = 0; nt < 2; ++nt) oc[mt][nt] = (f4)(0.f);
  float lacc[2][4] = {};

  const _Float16* bp = btf + (((size_t)qt * 36 + s * 18) * 128 + t) * 32;

  for (int kt = 0; kt < 18; ++kt) {
    const int k0 = (s * 18 + kt) * 64;
    // K + bias fragments straight from global (L2/L1-resident)
    h8 bfr[4];
#pragma unroll
    for (int r = 0; r < 4; ++r) bfr[r] = *(const h8*)(bp + r * 8);
    bp += 128 * 32;
    h8 kf[2][4];
#pragma unroll
    for (int ks = 0; ks < 2; ++ks)
#pragma unroll
      for (int mt = 0; mt < 4; ++mt)
        kf[ks][mt] = *(const h8*)(kp + (size_t)(k0 + mt * 16 + l15) * 64 +
                                  ks * 32 + quad * 8);

    // ---- S^T = K * Q^T ----
    f4 st[4][2];
#pragma unroll
    for (int mt = 0; mt < 4; ++mt)
#pragma unroll
      for (int nt = 0; nt < 2; ++nt) st[mt][nt] = (f4)(0.f);
#pragma unroll
    for (int ks = 0; ks < 2; ++ks)
#pragma unroll
      for (int mt = 0; mt < 4; ++mt)
#pragma unroll
        for (int nt = 0; nt < 2; ++nt)
          st[mt][nt] = __builtin_amdgcn_mfma_f32_16x16x32_f16(
              kf[ks][mt], qf[nt][ks], st[mt][nt], 0, 0, 0);

    // V fragments issued here so their latency overlaps softmax
    h8 vf[2][4];
#pragma unroll
    for (int ks = 0; ks < 2; ++ks)
#pragma unroll
      for (int mt = 0; mt < 4; ++mt)
        vf[ks][mt] = *(const h8*)(vp + (size_t)(mt * 16 + l15) * NN + k0 +
                                  ks * 32 + quad * 8);

    // ---- p = exp2(s*C1 + bias'), no max tracking ----
#pragma unroll
    for (int nt = 0; nt < 2; ++nt) {
      const int q = nt * 16 + l15;
#pragma unroll
      for (int mt = 0; mt < 4; ++mt) {
        h4 pk;
#pragma unroll
        for (int r = 0; r < 4; ++r) {
          const int j = nt * 16 + mt * 4 + r;
          const float bias = (float)bfr[j >> 3][j & 7];
          const float p = __builtin_exp2f(st[mt][nt][r] * C1 + bias);
          lacc[nt][r] += p;
          pk[r] = (_Float16)p;
        }
        *(h4*)&Ps[w][q][mt * 16 + quad * 4] = pk;  // wave-private
      }
    }

    // ---- O^T += V^T * P^T ----
#pragma unroll
    for (int ks = 0; ks < 2; ++ks) {
      h8 pf[2];
#pragma unroll
      for (int nt = 0; nt < 2; ++nt)
        pf[nt] = *(const h8*)&Ps[w][nt * 16 + l15][ks * 32 + quad * 8];
#pragma unroll
      for (int mt = 0; mt < 4; ++mt)
#pragma unroll
        for (int nt = 0; nt < 2; ++nt)
          oc[mt][nt] = __builtin_amdgcn_mfma_f32_16x16x32_f16(
              vf[ks][mt], pf[nt], oc[mt][nt], 0, 0, 0);
    }
  }

  // ---- epilogue ----
#pragma unroll
  for (int nt = 0; nt < 2; ++nt) {
    float l = lacc[nt][0] + lacc[nt][1] + lacc[nt][2] + lacc[nt][3];
    l += __shfl_xor(l, 16);
    l += __shfl_xor(l, 32);
    const float inv = 1.f / l;
    const int qi = n0 + nt * 16 + l15;
    _Float16* od = op + (size_t)s * BB * NN * DD +
                   ((size_t)b * NN + qi) * DD + h * 64;
#pragma unroll
    for (int mt = 0; mt < 4; ++mt) {
      const int dh = mt * 16 + quad * 4;
      h4 o = {(_Float16)(oc[mt][nt][0] * inv), (_Float16)(oc[mt][nt][1] * inv),
              (_Float16)(oc[mt][nt][2] * inv), (_Float16)(oc[mt][nt][3] * inv)};
      *(h4*)(od + dh) = o;
    }
    if (quad == 0)
      lp[(size_t)s * BB * NH * NN + ((size_t)b * NH + h) * NN + qi] = l;
  }
}

// ---------------------------------------------------------------------------
// Kernel 2b: combine K-split halves: ho = (o0*l0 + o1*l1) / (l0+l1)
// ---------------------------------------------------------------------------
__global__ __launch_bounds__(256) void comb_k(
    const _Float16* __restrict__ op, const float* __restrict__ lp,
    _Float16* __restrict__ ho)
{
  const int idx = blockIdx.x * 256 + threadIdx.x;  // B*NN*64
  const int d8 = idx & 63;
  const int bn = idx >> 6;
  const int n = bn % NN, b = bn / NN;
  const int h = d8 >> 3;
  const float l0 = lp[((size_t)b * NH + h) * NN + n];
  const float l1 = lp[(size_t)BB * NH * NN + ((size_t)b * NH + h) * NN + n];
  const float inv = 1.f / (l0 + l1);
  const float w0 = l0 * inv, w1 = l1 * inv;
  h8 o0 = *(const h8*)(op + (size_t)bn * DD + d8 * 8);
  h8 o1 = *(const h8*)(op + (size_t)BB * NN * DD + (size_t)bn * DD + d8 * 8);
  h8 r;
#pragma unroll
  for (int i = 0; i < 8; ++i)
    r[i] = (_Float16)((float)o0[i] * w0 + (float)o1[i] * w1);
  *(h8*)(ho + (size_t)bn * DD + d8 * 8) = r;
}

// ---------------------------------------------------------------------------
// Kernel 3: out MFMA GEMM, barrier-free, 1 wave per 64x64 tile, frags direct
// from global. out[b][o][n] = sum_d ho[n][d]*woh[o][d] + bias[o].
// ---------------------------------------------------------------------------
__global__ __launch_bounds__(64) void out_gemm_k(
    const _Float16* __restrict__ ho, const _Float16* __restrict__ woh,
    const float* __restrict__ bias, float* __restrict__ out)
{
  const int t = threadIdx.x;
  const int l15 = t & 15, quad = t >> 4;
  const int n0 = blockIdx.x * 64;
  const int o0 = blockIdx.y * 64;
  const int b  = blockIdx.z;
  const _Float16* hp = ho + ((size_t)b * NN + n0 + l15) * DD + quad * 8;
  const _Float16* wp = woh + (size_t)(o0 + l15) * DD + quad * 8;

  f4 acc[4][4];
#pragma unroll
  for (int mt = 0; mt < 4; ++mt)
#pragma unroll
    for (int nt = 0; nt < 4; ++nt) acc[mt][nt] = (f4)(0.f);

#pragma unroll 2
  for (int c0 = 0; c0 < DD; c0 += 32) {
    h8 hf[4], wf[4];
#pragma unroll
    for (int mt = 0; mt < 4; ++mt)
      hf[mt] = *(const h8*)(hp + (size_t)mt * 16 * DD + c0);
#pragma unroll
    for (int nt = 0; nt < 4; ++nt)
      wf[nt] = *(const h8*)(wp + (size_t)nt * 16 * DD + c0);
#pragma unroll
    for (int mt = 0; mt < 4; ++mt)
#pragma unroll
      for (int nt = 0; nt < 4; ++nt)
        acc[mt][nt] = __builtin_amdgcn_mfma_f32_16x16x32_f16(
            hf[mt], wf[nt], acc[mt][nt], 0, 0, 0);
  }

#pragma unroll
  for (int nt = 0; nt < 4; ++nt) {
    const int o = o0 + nt * 16 + l15;
    const float bv = bias[o];
#pragma unroll
    for (int mt = 0; mt < 4; ++mt) {
      const int token = n0 + mt * 16 + quad * 4;
      float4 v = {acc[mt][nt][0] + bv, acc[mt][nt][1] + bv,
                  acc[mt][nt][2] + bv, acc[mt][nt][3] + bv};
      *(float4*)(out + ((size_t)b * DD + o) * NN + token) = v;
    }
  }
}

extern "C" void kernel_launch(void* const* d_in, const int* in_sizes, int n_in,
                              void* d_out, int out_size, void* d_ws, size_t ws_size,
                              hipStream_t stream)
{
  (void)in_sizes; (void)n_in; (void)out_size; (void)ws_size;
  const float* x     = (const float*)d_in[0];
  const float* w_qkv = (const float*)d_in[1];
  const float* w_out = (const float*)d_in[2];
  const float* b_out = (const float*)d_in[3];
  const float* wav   = (const float*)d_in[4];
  float* out = (float*)d_out;

  const size_t SZ  = (size_t)BB * NH * NN * 64;   // 2,359,296
  const size_t BTF = (size_t)36 * 36 * 128 * 32;  // 5,308,416

  _Float16* qb  = (_Float16*)d_ws;
  _Float16* kb  = qb + SZ;
  _Float16* vb  = kb + SZ;
  _Float16* btf = vb + SZ;                 // later aliased by ho
  _Float16* op  = btf + BTF;               // 2*SZ partial O (f16, normalized)
  float*    lpf = (float*)(op + 2 * SZ);   // 2*B*NH*NN f32
  _Float16* woh = (_Float16*)(lpf + 2 * (size_t)BB * NH * NN);
  // aliases (lifetime-disjoint):
  _Float16* ho  = btf;       // combine output (btf dead after attn)
  _Float16* xt  = op;        // x^T f16 (dead after qkv_gemm)
  _Float16* wqh = op + SZ;   // w_qkv f16 (dead after qkv_gemm)
  // total ws: ~35.0 MB (same layout as R4)

  btf_k     <<<dim3(36, 36), 128, 0, stream>>>(wav, btf);
  tx_k      <<<dim3(NN / 32, CC / 32, BB), 256, 0, stream>>>(x, xt);
  convw_k   <<<dim3((D3 * CC + DD * DD) / 1024), 256, 0, stream>>>(w_qkv, w_out, wqh, woh);
  qkv_gemm_k<<<dim3(NN / 128, D3 / 128, BB), 256, 0, stream>>>(xt, wqh, qb, kb, vb);
  attn_k    <<<dim3(NN / 64 * 2, NH, BB), 128, 0, stream>>>(qb, kb, vb, btf, op, lpf);
  comb_k    <<<dim3((BB * NN * 64) / 256), 256, 0, stream>>>(op, lpf, ho);
  out_gemm_k<<<dim3(NN / 64, DD / 64, BB), 64, 0, stream>>>(ho, woh, b_out, out);
}

// Round 6
// 177.106 us; speedup vs baseline: 1.3044x; 1.3044x over previous
//
#include <hip/hip_runtime.h>
#include <math.h>

#define BB 2
#define CC 512
#define NN 2304
#define NH 8
#define DD 512
#define D3 1536
#define WIDTH 48
#define C1 0.18033688f  // 0.125 * log2(e)

typedef _Float16 h8 __attribute__((ext_vector_type(8)));
typedef _Float16 h4 __attribute__((ext_vector_type(4)));
typedef _Float16 h2 __attribute__((ext_vector_type(2)));
typedef float f4 __attribute__((ext_vector_type(4)));

__device__ __forceinline__ void gload16(const void* g, void* s) {
  __builtin_amdgcn_global_load_lds(
      (const __attribute__((address_space(1))) unsigned int*)g,
      (__attribute__((address_space(3))) unsigned int*)s, 16, 0, 0);
}

// ---------------------------------------------------------------------------
// Kernel 0: Fresnel bias table in MFMA C-fragment order, pre-scaled by log2e.
// btf[qtile 36][ktile 36][tid 128][j 32], j = nt*16 + mt*4 + r:
//   query = qtile*64 + (tid>>6)*32 + nt*16 + (tid&15)
//   key   = ktile*64 + mt*16 + ((tid>>4)&3)*4 + r
// ---------------------------------------------------------------------------
__global__ __launch_bounds__(128) void btf_k(const float* __restrict__ wavp,
                                             _Float16* __restrict__ btf)
{
  const int t = threadIdx.x;
  const int qbk = blockIdx.x, ktk = blockIdx.y;
  const int w = t >> 6, quad = (t >> 4) & 3, l15 = t & 15;
  const float pc = 6.283185307179586f / (fabsf(wavp[0]) * (float)WIDTH + 1e-6f);
  _Float16* o = btf + (((size_t)qbk * 36 + ktk) * 128 + t) * 32;
#pragma unroll
  for (int g = 0; g < 4; ++g) {
    h8 v;
#pragma unroll
    for (int e = 0; e < 8; ++e) {
      const int j = g * 8 + e;
      const int nt = j >> 4, mt = (j >> 2) & 3, r = j & 3;
      const int q = qbk * 64 + w * 32 + nt * 16 + l15;
      const int k = ktk * 64 + mt * 16 + quad * 4 + r;
      const float dy = (float)(q / WIDTH) - (float)(k / WIDTH);
      const float dx = (float)(q % WIDTH) - (float)(k % WIDTH);
      const float dist = sqrtf(dy * dy + dx * dx + 1e-8f);
      v[e] = (_Float16)(0.1f * __cosf(dist * pc) * 1.44269504f);
    }
    *(h8*)(o + g * 8) = v;
  }
}

// ---------------------------------------------------------------------------
// Kernel 0b: transpose-convert x[b][c][n] fp32 -> xt[b][n][c] f16
// ---------------------------------------------------------------------------
__global__ __launch_bounds__(256) void tx_k(const float* __restrict__ x,
                                            _Float16* __restrict__ xt)
{
  __shared__ float Ls[32][33];
  const int t = threadIdx.x;
  const int n0 = blockIdx.x * 32, c0 = blockIdx.y * 32, b = blockIdx.z;
#pragma unroll
  for (int p = 0; p < 4; ++p) {
    const int cl = (t >> 5) + p * 8, nl = t & 31;
    Ls[cl][nl] = x[((size_t)b * CC + c0 + cl) * NN + n0 + nl];
  }
  __syncthreads();
#pragma unroll
  for (int p = 0; p < 2; ++p) {
    const int nl = (t >> 4) + p * 16, cl = (t & 15) * 2;
    h2 v = {(_Float16)Ls[cl][nl], (_Float16)Ls[cl + 1][nl]};
    *(h2*)(xt + ((size_t)b * NN + n0 + nl) * CC + c0 + cl) = v;
  }
}

// ---------------------------------------------------------------------------
// Kernel 0c: convert w_qkv and w_out fp32 -> f16
// ---------------------------------------------------------------------------
__global__ __launch_bounds__(256) void convw_k(const float* __restrict__ wq,
                                               const float* __restrict__ wo,
                                               _Float16* __restrict__ wqh,
                                               _Float16* __restrict__ woh)
{
  const int idx = blockIdx.x * 256 + threadIdx.x;
  const int NQ = (D3 * CC) / 4;
  if (idx < NQ) {
    float4 v = *(const float4*)(wq + (size_t)idx * 4);
    h4 o = {(_Float16)v.x, (_Float16)v.y, (_Float16)v.z, (_Float16)v.w};
    *(h4*)(wqh + (size_t)idx * 4) = o;
  } else {
    const int j = idx - NQ;
    float4 v = *(const float4*)(wo + (size_t)j * 4);
    h4 o = {(_Float16)v.x, (_Float16)v.y, (_Float16)v.z, (_Float16)v.w};
    *(h4*)(woh + (size_t)j * 4) = o;
  }
}

// ---------------------------------------------------------------------------
// Kernel 1: qkv MFMA GEMM. 64x64 tile, ONE wave per block (grid 1728 =
// 6.75 blocks/CU), double-buffered global_load_lds staging so the next
// K-chunk is in flight during the current chunk's MFMAs (m97 pattern).
// q/k blocks: D[d][token] -> [n][dh] stores. v blocks: swapped args ->
// D[token][d] -> [dh][n] stores.
// ---------------------------------------------------------------------------
__global__ __launch_bounds__(64) void qkv_gemm_k(
    const _Float16* __restrict__ xt, const _Float16* __restrict__ wqh,
    _Float16* __restrict__ qb, _Float16* __restrict__ kb,
    _Float16* __restrict__ vb)
{
  __shared__ _Float16 Xs[2][64][32];
  __shared__ _Float16 Ws[2][64][32];
  const int t = threadIdx.x;
  const int l15 = t & 15, quad = t >> 4;
  const int n0 = blockIdx.x * 64;
  const int d0 = blockIdx.y * 64;
  const int b  = blockIdx.z;
  const bool isv = (d0 >= 2 * DD);
  const _Float16* xb = xt + (size_t)b * NN * CC;
  const int srow = t >> 2, scol = (t & 3) * 8;  // staging: 4 lanes per row

  f4 acc[4][4];
#pragma unroll
  for (int mt = 0; mt < 4; ++mt)
#pragma unroll
    for (int nt = 0; nt < 4; ++nt) acc[mt][nt] = (f4)(0.f);

  // stage chunk c0 into buffer bf
  auto stage = [&](int bf, int c0) {
#pragma unroll
    for (int ci = 0; ci < 4; ++ci) {
      const int row = ci * 16 + srow;
      gload16(xb + (size_t)(n0 + row) * CC + c0 + scol,
              &Xs[bf][0][0] + ci * 512);
      gload16(wqh + (size_t)(d0 + row) * CC + c0 + scol,
              &Ws[bf][0][0] + ci * 512);
    }
  };

  stage(0, 0);
  for (int i = 0; i < 16; ++i) {
    const int cur = i & 1;
    __syncthreads();  // drains vmcnt -> stage(cur) complete
    if (i < 15) stage(cur ^ 1, (i + 1) * 32);  // in flight during compute
    h8 wfr[4], xfr[4];
#pragma unroll
    for (int mt = 0; mt < 4; ++mt)
      wfr[mt] = *(const h8*)&Ws[cur][mt * 16 + l15][quad * 8];
#pragma unroll
    for (int nt = 0; nt < 4; ++nt)
      xfr[nt] = *(const h8*)&Xs[cur][nt * 16 + l15][quad * 8];
    if (!isv) {
#pragma unroll
      for (int mt = 0; mt < 4; ++mt)
#pragma unroll
        for (int nt = 0; nt < 4; ++nt)
          acc[mt][nt] = __builtin_amdgcn_mfma_f32_16x16x32_f16(
              wfr[mt], xfr[nt], acc[mt][nt], 0, 0, 0);
    } else {
#pragma unroll
      for (int mt = 0; mt < 4; ++mt)
#pragma unroll
        for (int nt = 0; nt < 4; ++nt)
          acc[mt][nt] = __builtin_amdgcn_mfma_f32_16x16x32_f16(
              xfr[nt], wfr[mt], acc[mt][nt], 0, 0, 0);
    }
  }

  if (!isv) {
    const int which = d0 >> 9;  // 0 = q, 1 = k
    _Float16* buf = which == 0 ? qb : kb;
    const int h = (d0 & 511) >> 6;
#pragma unroll
    for (int mt = 0; mt < 4; ++mt) {
      const int dh = mt * 16 + quad * 4;
#pragma unroll
      for (int nt = 0; nt < 4; ++nt) {
        const int token = n0 + nt * 16 + l15;
        h4 o = {(_Float16)acc[mt][nt][0], (_Float16)acc[mt][nt][1],
                (_Float16)acc[mt][nt][2], (_Float16)acc[mt][nt][3]};
        *(h4*)(buf + (((size_t)b * NH + h) * NN + token) * 64 + dh) = o;
      }
    }
  } else {
    const int h = (d0 - 2 * DD) >> 6;
#pragma unroll
    for (int mt = 0; mt < 4; ++mt) {
      const int dh = mt * 16 + l15;
#pragma unroll
      for (int nt = 0; nt < 4; ++nt) {
        const int token = n0 + nt * 16 + quad * 4;
        h4 o = {(_Float16)acc[mt][nt][0], (_Float16)acc[mt][nt][1],
                (_Float16)acc[mt][nt][2], (_Float16)acc[mt][nt][3]};
        *(h4*)(vb + (((size_t)b * NH + h) * 64 + dh) * NN + token) = o;
      }
    }
  }
}

// ---------------------------------------------------------------------------
// Kernel 2: MFMA flash attention, K-split x2, LDS-staged K/V (R4 structure)
// with software-pipelined prefetch: next tile's global->reg loads issued
// right after the write barrier so their latency overlaps QK/softmax/PV.
// No-max softmax (p = exp2(s*C1 + bias')), bias from frag-ordered table.
// ---------------------------------------------------------------------------
__global__ __launch_bounds__(128, 3) void attn_k(
    const _Float16* __restrict__ qb, const _Float16* __restrict__ kb,
    const _Float16* __restrict__ vb, const _Float16* __restrict__ btf,
    _Float16* __restrict__ op, float* __restrict__ lp)
{
  __shared__ _Float16 Ks[64][72];
  __shared__ _Float16 Vs[64][72];
  __shared__ _Float16 Ps[2][32][72];

  const int t    = threadIdx.x;
  const int lane = t & 63;
  const int w    = t >> 6;
  const int l15  = lane & 15;
  const int quad = lane >> 4;
  const int qt = blockIdx.x >> 1;
  const int s  = blockIdx.x & 1;
  const int h = blockIdx.y, b = blockIdx.z;
  const int n0 = qt * 64;
  const size_t base = ((size_t)b * NH + h) * NN * 64;
  const _Float16* qp = qb + base;
  const _Float16* kp = kb + base;
  const _Float16* vp = vb + base;  // [dh][n]

  h8 qf[2][2];
#pragma unroll
  for (int nt = 0; nt < 2; ++nt)
#pragma unroll
    for (int ks = 0; ks < 2; ++ks)
      qf[nt][ks] = *(const h8*)(qp + (size_t)(n0 + w * 32 + nt * 16 + l15) * 64 +
                                ks * 32 + quad * 8);

  f4 oc[4][2];
#pragma unroll
  for (int mt = 0; mt < 4; ++mt)
#pragma unroll
    for (int nt = 0; nt < 2; ++nt) oc[mt][nt] = (f4)(0.f);
  float lacc[2][4] = {};

  const int srow = t >> 3, soff = (t & 7) * 8;  // staging: 8 lanes per row
  const _Float16* bp = btf + (((size_t)qt * 36 + s * 18) * 128 + t) * 32;

  // prologue: load tile 0 into registers
  h8 kr[4], vr[4], br[4];
  {
    const int k0 = s * 18 * 64;
#pragma unroll
    for (int r = 0; r < 4; ++r) {
      const int row = srow + r * 16;
      kr[r] = *(const h8*)(kp + (size_t)(k0 + row) * 64 + soff);
      vr[r] = *(const h8*)(vp + (size_t)row * NN + k0 + soff);
      br[r] = *(const h8*)(bp + r * 8);
    }
  }

  for (int kt = 0; kt < 18; ++kt) {
    __syncthreads();  // all waves done reading previous tile's LDS
#pragma unroll
    for (int r = 0; r < 4; ++r) {
      const int row = srow + r * 16;
      *(h8*)&Ks[row][soff] = kr[r];
      *(h8*)&Vs[row][soff] = vr[r];
    }
    h8 bfr[4];
#pragma unroll
    for (int r = 0; r < 4; ++r) bfr[r] = br[r];
    __syncthreads();

    // issue next tile's loads NOW — latency overlaps the compute below
    if (kt < 17) {
      const int k0n = (s * 18 + kt + 1) * 64;
      bp += 128 * 32;
#pragma unroll
      for (int r = 0; r < 4; ++r) {
        const int row = srow + r * 16;
        kr[r] = *(const h8*)(kp + (size_t)(k0n + row) * 64 + soff);
        vr[r] = *(const h8*)(vp + (size_t)row * NN + k0n + soff);
        br[r] = *(const h8*)(bp + r * 8);
      }
    }

    // ---- S^T = K * Q^T ----
    f4 st[4][2];
#pragma unroll
    for (int mt = 0; mt < 4; ++mt)
#pragma unroll
      for (int nt = 0; nt < 2; ++nt) st[mt][nt] = (f4)(0.f);
#pragma unroll
    for (int ks = 0; ks < 2; ++ks)
#pragma unroll
      for (int mt = 0; mt < 4; ++mt) {
        h8 kf = *(const h8*)&Ks[mt * 16 + l15][ks * 32 + quad * 8];
#pragma unroll
        for (int nt = 0; nt < 2; ++nt)
          st[mt][nt] = __builtin_amdgcn_mfma_f32_16x16x32_f16(
              kf, qf[nt][ks], st[mt][nt], 0, 0, 0);
      }

    // ---- p = exp2(s*C1 + bias'), no max tracking ----
#pragma unroll
    for (int nt = 0; nt < 2; ++nt) {
      const int q = nt * 16 + l15;
#pragma unroll
      for (int mt = 0; mt < 4; ++mt) {
        h4 pk;
#pragma unroll
        for (int r = 0; r < 4; ++r) {
          const int j = nt * 16 + mt * 4 + r;
          const float bias = (float)bfr[j >> 3][j & 7];
          const float p = __builtin_exp2f(st[mt][nt][r] * C1 + bias);
          lacc[nt][r] += p;
          pk[r] = (_Float16)p;
        }
        *(h4*)&Ps[w][q][mt * 16 + quad * 4] = pk;  // wave-private
      }
    }

    // ---- O^T += V^T * P^T ----
#pragma unroll
    for (int ks = 0; ks < 2; ++ks) {
      h8 pf[2];
#pragma unroll
      for (int nt = 0; nt < 2; ++nt)
        pf[nt] = *(const h8*)&Ps[w][nt * 16 + l15][ks * 32 + quad * 8];
#pragma unroll
      for (int mt = 0; mt < 4; ++mt) {
        h8 vf = *(const h8*)&Vs[mt * 16 + l15][ks * 32 + quad * 8];
#pragma unroll
        for (int nt = 0; nt < 2; ++nt)
          oc[mt][nt] = __builtin_amdgcn_mfma_f32_16x16x32_f16(
              vf, pf[nt], oc[mt][nt], 0, 0, 0);
      }
    }
  }

  // ---- epilogue ----
#pragma unroll
  for (int nt = 0; nt < 2; ++nt) {
    float l = lacc[nt][0] + lacc[nt][1] + lacc[nt][2] + lacc[nt][3];
    l += __shfl_xor(l, 16);
    l += __shfl_xor(l, 32);
    const float inv = 1.f / l;
    const int qi = n0 + w * 32 + nt * 16 + l15;
    _Float16* od = op + (size_t)s * BB * NN * DD +
                   ((size_t)b * NN + qi) * DD + h * 64;
#pragma unroll
    for (int mt = 0; mt < 4; ++mt) {
      const int dh = mt * 16 + quad * 4;
      h4 o = {(_Float16)(oc[mt][nt][0] * inv), (_Float16)(oc[mt][nt][1] * inv),
              (_Float16)(oc[mt][nt][2] * inv), (_Float16)(oc[mt][nt][3] * inv)};
      *(h4*)(od + dh) = o;
    }
    if (quad == 0)
      lp[(size_t)s * BB * NH * NN + ((size_t)b * NH + h) * NN + qi] = l;
  }
}

// ---------------------------------------------------------------------------
// Kernel 2b: combine K-split halves: ho = (o0*l0 + o1*l1) / (l0+l1)
// ---------------------------------------------------------------------------
__global__ __launch_bounds__(256) void comb_k(
    const _Float16* __restrict__ op, const float* __restrict__ lp,
    _Float16* __restrict__ ho)
{
  const int idx = blockIdx.x * 256 + threadIdx.x;  // B*NN*64
  const int d8 = idx & 63;
  const int bn = idx >> 6;
  const int n = bn % NN, b = bn / NN;
  const int h = d8 >> 3;
  const float l0 = lp[((size_t)b * NH + h) * NN + n];
  const float l1 = lp[(size_t)BB * NH * NN + ((size_t)b * NH + h) * NN + n];
  const float inv = 1.f / (l0 + l1);
  const float w0 = l0 * inv, w1 = l1 * inv;
  h8 o0 = *(const h8*)(op + (size_t)bn * DD + d8 * 8);
  h8 o1 = *(const h8*)(op + (size_t)BB * NN * DD + (size_t)bn * DD + d8 * 8);
  h8 r;
#pragma unroll
  for (int i = 0; i < 8; ++i)
    r[i] = (_Float16)((float)o0[i] * w0 + (float)o1[i] * w1);
  *(h8*)(ho + (size_t)bn * DD + d8 * 8) = r;
}

// ---------------------------------------------------------------------------
// Kernel 3: out MFMA GEMM, 64x64 tile, 1 wave, double-buffered gload16.
// out[b][o][n] = sum_d ho[n][d]*woh[o][d] + bias[o].
// ---------------------------------------------------------------------------
__global__ __launch_bounds__(64) void out_gemm_k(
    const _Float16* __restrict__ ho, const _Float16* __restrict__ woh,
    const float* __restrict__ bias, float* __restrict__ out)
{
  __shared__ _Float16 Hs[2][64][32];
  __shared__ _Float16 Ws2[2][64][32];
  const int t = threadIdx.x;
  const int l15 = t & 15, quad = t >> 4;
  const int n0 = blockIdx.x * 64;
  const int o0 = blockIdx.y * 64;
  const int b  = blockIdx.z;
  const int srow = t >> 2, scol = (t & 3) * 8;

  f4 acc[4][4];
#pragma unroll
  for (int mt = 0; mt < 4; ++mt)
#pragma unroll
    for (int nt = 0; nt < 4; ++nt) acc[mt][nt] = (f4)(0.f);

  auto stage = [&](int bf, int c0) {
#pragma unroll
    for (int ci = 0; ci < 4; ++ci) {
      const int row = ci * 16 + srow;
      gload16(ho + ((size_t)b * NN + n0 + row) * DD + c0 + scol,
              &Hs[bf][0][0] + ci * 512);
      gload16(woh + (size_t)(o0 + row) * DD + c0 + scol,
              &Ws2[bf][0][0] + ci * 512);
    }
  };

  stage(0, 0);
  for (int i = 0; i < 16; ++i) {
    const int cur = i & 1;
    __syncthreads();
    if (i < 15) stage(cur ^ 1, (i + 1) * 32);
    h8 hf[4], wf[4];
#pragma unroll
    for (int mt = 0; mt < 4; ++mt)
      hf[mt] = *(const h8*)&Hs[cur][mt * 16 + l15][quad * 8];
#pragma unroll
    for (int nt = 0; nt < 4; ++nt)
      wf[nt] = *(const h8*)&Ws2[cur][nt * 16 + l15][quad * 8];
#pragma unroll
    for (int mt = 0; mt < 4; ++mt)
#pragma unroll
      for (int nt = 0; nt < 4; ++nt)
        acc[mt][nt] = __builtin_amdgcn_mfma_f32_16x16x32_f16(
            hf[mt], wf[nt], acc[mt][nt], 0, 0, 0);
  }

#pragma unroll
  for (int nt = 0; nt < 4; ++nt) {
    const int o = o0 + nt * 16 + l15;
    const float bv = bias[o];
#pragma unroll
    for (int mt = 0; mt < 4; ++mt) {
      const int token = n0 + mt * 16 + quad * 4;
      float4 v = {acc[mt][nt][0] + bv, acc[mt][nt][1] + bv,
                  acc[mt][nt][2] + bv, acc[mt][nt][3] + bv};
      *(float4*)(out + ((size_t)b * DD + o) * NN + token) = v;
    }
  }
}

extern "C" void kernel_launch(void* const* d_in, const int* in_sizes, int n_in,
                              void* d_out, int out_size, void* d_ws, size_t ws_size,
                              hipStream_t stream)
{
  (void)in_sizes; (void)n_in; (void)out_size; (void)ws_size;
  const float* x     = (const float*)d_in[0];
  const float* w_qkv = (const float*)d_in[1];
  const float* w_out = (const float*)d_in[2];
  const float* b_out = (const float*)d_in[3];
  const float* wav   = (const float*)d_in[4];
  float* out = (float*)d_out;

  const size_t SZ  = (size_t)BB * NH * NN * 64;   // 2,359,296
  const size_t BTF = (size_t)36 * 36 * 128 * 32;  // 5,308,416

  _Float16* qb  = (_Float16*)d_ws;
  _Float16* kb  = qb + SZ;
  _Float16* vb  = kb + SZ;
  _Float16* btf = vb + SZ;                 // later aliased by ho
  _Float16* op  = btf + BTF;               // 2*SZ partial O (f16, normalized)
  float*    lpf = (float*)(op + 2 * SZ);   // 2*B*NH*NN f32
  _Float16* woh = (_Float16*)(lpf + 2 * (size_t)BB * NH * NN);
  // aliases (lifetime-disjoint):
  _Float16* ho  = btf;       // combine output (btf dead after attn)
  _Float16* xt  = op;        // x^T f16 (dead after qkv_gemm)
  _Float16* wqh = op + SZ;   // w_qkv f16 (dead after qkv_gemm)
  // total ws: ~35.0 MB (same layout as R4)

  btf_k     <<<dim3(36, 36), 128, 0, stream>>>(wav, btf);
  tx_k      <<<dim3(NN / 32, CC / 32, BB), 256, 0, stream>>>(x, xt);
  convw_k   <<<dim3((D3 * CC + DD * DD) / 1024), 256, 0, stream>>>(w_qkv, w_out, wqh, woh);
  qkv_gemm_k<<<dim3(NN / 64, D3 / 64, BB), 64, 0, stream>>>(xt, wqh, qb, kb, vb);
  attn_k    <<<dim3(NN / 64 * 2, NH, BB), 128, 0, stream>>>(qb, kb, vb, btf, op, lpf);
  comb_k    <<<dim3((BB * NN * 64) / 256), 256, 0, stream>>>(op, lpf, ho);
  out_gemm_k<<<dim3(NN / 64, DD / 64, BB), 64, 0, stream>>>(ho, woh, b_out, out);
}